// Round 9
// baseline (260.244 us; speedup 1.0000x reference)
//
#include <hip/hip_runtime.h>

typedef unsigned short u16;
typedef unsigned int u32;
typedef _Float16 f16;
typedef __attribute__((ext_vector_type(8))) f16 half8;   // 8 fp16 = 4 VGPR MFMA operand
typedef __attribute__((ext_vector_type(4))) f16 half4;
typedef __attribute__((ext_vector_type(4))) float f32x4;

#define MFMA16(a, b, c) __builtin_amdgcn_mfma_f32_16x16x32_f16((a), (b), (c), 0, 0, 0)

static __device__ __forceinline__ void gload16(const void* g, void* l) {
  __builtin_amdgcn_global_load_lds(
      (const __attribute__((address_space(1))) void*)g,
      (__attribute__((address_space(3))) void*)l, 16, 0, 0);
}
// swizzled LDS read: rows are 128B; physical col = col ^ ((row&7)<<4)  (T2 st-style swizzle)
static __device__ __forceinline__ half8 lds8h(const f16* base, int row, int colb) {
  int phys = row * 128 + (colb ^ ((row & 7) << 4));
  return *(const half8*)((const char*)base + phys);
}

// ---------------- convert: fp32 -> fp16 (single; products exact in fp32 accum) ----------------
__global__ void cvt_kernel(const float* __restrict__ in, f16* __restrict__ o, int n4) {
  int i = blockIdx.x * blockDim.x + threadIdx.x;
  int stride = gridDim.x * blockDim.x;
  for (; i < n4; i += stride) {
    float4 v = ((const float4*)in)[i];
    half4 h;
    h.x = (f16)v.x; h.y = (f16)v.y; h.z = (f16)v.z; h.w = (f16)v.w;
    *(half4*)(o + (size_t)i * 4) = h;
  }
}

// ---------------- QKV projection GEMM (fp16, LDS-staged vector epilogue) ----------------
// C[8192][3072] = X[8192][1024] @ W[3072][1024]^T + b
// Fragment layout out: [bh][t(32)][ki(2)][ni(4)][lane(64)][e(8)].
// Key fact: per thread h_idx==wn, t_idx==wm -> each wave's values fill ONE 8KB region.
// Epilogue stages 32KB in LDS (reusing sA/sB), then 8x dwordx4 per lane.
__global__ __launch_bounds__(256, 2) void gemm_qkv(
    const f16* __restrict__ xf, const f16* __restrict__ wf,
    const float* __restrict__ bias,
    f16* __restrict__ qf, f16* __restrict__ kf, f16* __restrict__ vf) {
  __shared__ __align__(16) f16 smem[16384];          // sA | sB, reused as 4x4096 staging
  f16* sA = smem;
  f16* sB = smem + 8192;
  const int L = blockIdx.x;
  const int swz = (L & 7) * 192 + (L >> 3);   // 1536/8 = 192; bijective
  const int ct = swz % 24, mt = swz / 24;
  const int c0 = ct * 128, m0 = mt * 128;
  const int tid = threadIdx.x, lane = tid & 63, w = tid >> 6;
  const int wm = w >> 1, wn = w & 1;
  f32x4 acc[4][4] = {};

  for (int t = 0; t < 16; ++t) {
    const int k0 = t * 64;
    for (int j = 0; j < 4; ++j) {
      int chunk = w * 4 + j;
      int r = chunk * 8 + (lane >> 3);
      int cb = (lane & 7) * 16;
      int cbs = cb ^ ((r & 7) << 4);    // inverse-swizzled global source, linear LDS dest
      gload16((const char*)(xf + (size_t)(m0 + r) * 1024 + k0) + cbs, (char*)sA + chunk * 1024);
      gload16((const char*)(wf + (size_t)(c0 + r) * 1024 + k0) + cbs, (char*)sB + chunk * 1024);
    }
    asm volatile("s_waitcnt vmcnt(0)" ::: "memory");
    __syncthreads();

    for (int ki = 0; ki < 2; ++ki) {
      const int colb = (ki * 32 + (lane >> 4) * 8) * 2;
      half8 a[4], bfr[4];
      for (int mi = 0; mi < 4; ++mi)
        a[mi] = lds8h(sA, wm * 64 + mi * 16 + (lane & 15), colb);
      for (int ni = 0; ni < 4; ++ni)
        bfr[ni] = lds8h(sB, wn * 64 + ni * 16 + (lane & 15), colb);
      for (int mi = 0; mi < 4; ++mi)
        for (int ni = 0; ni < 4; ++ni)
          acc[mi][ni] = MFMA16(a[mi], bfr[ni], acc[mi][ni]);
    }
    __syncthreads();
  }

  // ---- epilogue: bias + LDS-staged fragment stores ----
  const int g = lane >> 4, cl = lane & 15;
  const int b = m0 >> 11;
  const int n0t = (m0 & 2047) >> 6;
  const int reg = wn * 2 + wm;           // this wave's staging region
  if (ct < 16) {
    for (int ni = 0; ni < 4; ++ni) {
      const int c = c0 + wn * 64 + ni * 16 + cl;
      const float bv = bias[c];
      const int p = ni * 16 + cl;        // == c & 63
      const int kki = p >> 5, lhi = (p >> 3) & 3, e = p & 7;
      for (int mi = 0; mi < 4; ++mi) {
        int off = reg * 4096 + (kki * 4 + mi) * 512 + lhi * 128 + e;
        for (int i = 0; i < 4; ++i)
          smem[off + (g * 4 + i) * 8] = (f16)(acc[mi][ni][i] + bv);
      }
    }
  } else {
    for (int ni = 0; ni < 4; ++ni) {
      const int c = c0 + wn * 64 + ni * 16 + cl;
      const float bv = bias[c];
      const int p = ni * 16 + cl;
      const int niv = p >> 4, lane_lo = p & 15;
      for (int mi = 0; mi < 4; ++mi) {
        const int kki = mi >> 1;
        for (int i = 0; i < 4; ++i) {
          const int lhi = (mi & 1) * 2 + (g >> 1);
          const int e = (g & 1) * 4 + i;
          smem[reg * 4096 + (kki * 4 + niv) * 512 + (lhi * 16 + lane_lo) * 8 + e] =
              (f16)(acc[mi][ni][i] + bv);
        }
      }
    }
  }
  __syncthreads();
  // copy out: wave w copies the region IT wrote (rw = wn*2+wm of itself)
  {
    const int rw = (w & 1) * 2 + (w >> 1);
    const int h_idx = rw >> 1, t_idx = rw & 1;
    f16* dst; int hbase;
    if (ct < 8)       { dst = qf; hbase = c0 >> 6; }
    else if (ct < 16) { dst = kf; hbase = (c0 - 1024) >> 6; }
    else              { dst = vf; hbase = (c0 - 2048) >> 6; }
    size_t gbase = (((size_t)(b * 16 + hbase + h_idx) * 32) + (size_t)(n0t + t_idx)) * 4096;
    for (int j = 0; j < 8; ++j)
      *(float4*)(dst + gbase + (size_t)j * 512 + (size_t)lane * 8) =
          *(const float4*)(smem + rw * 4096 + j * 512 + lane * 8);
  }
}

// ---------------- flash attention (fp16, swapped softmax, defer-max) ----------------
// Grid 1024: xcd=bid&7, bh=xcd*8+(li>>4), qt=li&15; 4 waves x 32 q-rows.
// Swapped QK^T: S^T = K.Q^T -> col=q=lane&15, row=kv; in-register row softmax + 2 shfls.
// T13 defer-max (THR=8): skip corr/rescale while tile max stays within 8 of running max.
__global__ __launch_bounds__(256, 4) void attn_kernel(
    const f16* __restrict__ qf, const f16* __restrict__ kf,
    const f16* __restrict__ vf, float* __restrict__ out) {
  __shared__ __align__(16) f16 pbuf[4][32 * 72];

  const int tid = threadIdx.x, lane = tid & 63, w = tid >> 6;
  const int bid = blockIdx.x;
  const int xcd = bid & 7, li = bid >> 3;
  const int bh = xcd * 8 + (li >> 4);
  const int qt = li & 15;
  const int g = lane >> 4, q = lane & 15;
  const size_t bhbase = (size_t)bh * 32 * 4096;   // per t: 2ki*4ni*512 = 4096 f16

  // Q fragments — used as B-operand (same per-lane layout as A)
  half8 qfr[2][2];
  for (int mi = 0; mi < 2; ++mi) {
    int idx = 2 * w + mi;
    int t = qt * 2 + (idx >> 2), nni = idx & 3;
    for (int ki = 0; ki < 2; ++ki) {
      size_t a = bhbase + (((size_t)t * 2 + ki) * 4 + nni) * 512 + (size_t)lane * 8;
      qfr[mi][ki] = *(const half8*)(qf + a);
    }
  }

  f32x4 oaccT[2][4] = {};                 // [mi][d-block]: col=q, row=d
  float mrow[2], lrow[2];
  for (int mi = 0; mi < 2; ++mi) { mrow[mi] = -3.0e38f; lrow[mi] = 0.f; }

  for (int t = 0; t < 32; ++t) {
    const size_t tb = bhbase + (size_t)t * 4096;

    // S^T = K Q^T ; K fragments as A-operand, straight from global (L2-resident)
    f32x4 sacc[2][4] = {};                // [mi][kv-block]: col=q, row=kv
    for (int ki = 0; ki < 2; ++ki) {
      half8 khf[4];
      for (int ni = 0; ni < 4; ++ni)
        khf[ni] = *(const half8*)(kf + tb + (((size_t)ki * 4 + ni) * 64 + lane) * 8);
      for (int mi = 0; mi < 2; ++mi)
        for (int ni = 0; ni < 4; ++ni)
          sacc[mi][ni] = MFMA16(khf[ni], qfr[mi][ki], sacc[mi][ni]);
    }

    // issue V fragment loads; latency hides under softmax
    half8 vfr[2][4];
    for (int ki = 0; ki < 2; ++ki)
      for (int ni = 0; ni < 4; ++ni)
        vfr[ki][ni] = *(const half8*)(vf + tb + (((size_t)ki * 4 + ni) * 64 + lane) * 8);

    // softmax: per mi, each lane owns q-row = lane&15; 16 kv values in-register
    for (int mi = 0; mi < 2; ++mi) {
      float a0 = fmaxf(fmaxf(sacc[mi][0][0], sacc[mi][0][1]), fmaxf(sacc[mi][0][2], sacc[mi][0][3]));
      float a1 = fmaxf(fmaxf(sacc[mi][1][0], sacc[mi][1][1]), fmaxf(sacc[mi][1][2], sacc[mi][1][3]));
      float a2 = fmaxf(fmaxf(sacc[mi][2][0], sacc[mi][2][1]), fmaxf(sacc[mi][2][2], sacc[mi][2][3]));
      float a3 = fmaxf(fmaxf(sacc[mi][3][0], sacc[mi][3][1]), fmaxf(sacc[mi][3][2], sacc[mi][3][3]));
      float mx = fmaxf(fmaxf(a0, a1), fmaxf(a2, a3));
      mx = fmaxf(mx, __shfl_xor(mx, 16));
      mx = fmaxf(mx, __shfl_xor(mx, 32));
      float mnew;
      if (__all(mx <= mrow[mi] + 8.f)) {
        mnew = mrow[mi];                    // defer: P bounded by e^8, no rescale
      } else {
        mnew = fmaxf(mrow[mi], mx);
        float corr = __expf(mrow[mi] - mnew);
        mrow[mi] = mnew;
        lrow[mi] *= corr;
        for (int ni = 0; ni < 4; ++ni)
          for (int i = 0; i < 4; ++i) oaccT[mi][ni][i] *= corr;
      }
      float rs = 0.f;
      const int prow = mi * 16 + q;
      for (int ni = 0; ni < 4; ++ni) {
        float p0 = __expf(sacc[mi][ni][0] - mnew);
        float p1 = __expf(sacc[mi][ni][1] - mnew);
        float p2 = __expf(sacc[mi][ni][2] - mnew);
        float p3 = __expf(sacc[mi][ni][3] - mnew);
        rs += (p0 + p1) + (p2 + p3);
        half4 pk;
        pk.x = (f16)p0; pk.y = (f16)p1; pk.z = (f16)p2; pk.w = (f16)p3;
        *(half4*)&pbuf[w][prow * 72 + ni * 16 + g * 4] = pk;
      }
      rs += __shfl_xor(rs, 16);
      rs += __shfl_xor(rs, 32);
      lrow[mi] += rs;
    }

    // O^T += V^T P^T  (A = vf fragment rows=d; B = P rows=q from per-wave pbuf)
    for (int ki = 0; ki < 2; ++ki) {
      half8 pf[2];
      for (int mi = 0; mi < 2; ++mi)
        pf[mi] = *(const half8*)&pbuf[w][(mi * 16 + q) * 72 + ki * 32 + g * 8];
      for (int ni = 0; ni < 4; ++ni)
        for (int mi = 0; mi < 2; ++mi)
          oaccT[mi][ni] = MFMA16(vfr[ki][ni], pf[mi], oaccT[mi][ni]);
    }
  }

  // epilogue: O^T/l -> out (faithful (B,H,N,pd) flat, fp32). col=q, row=d.
  for (int mi = 0; mi < 2; ++mi) {
    float inv = 1.f / lrow[mi];
    int grow = qt * 128 + w * 32 + mi * 16 + q;
    size_t obase = ((size_t)bh * 2048 + grow) * 64;
    for (int ni = 0; ni < 4; ++ni)
      for (int i = 0; i < 4; ++i)
        out[obase + ni * 16 + g * 4 + i] = oaccT[mi][ni][i] * inv;
  }
}

extern "C" void kernel_launch(void* const* d_in, const int* in_sizes, int n_in,
                              void* d_out, int out_size, void* d_ws, size_t ws_size,
                              hipStream_t stream) {
  (void)in_sizes; (void)n_in; (void)out_size; (void)ws_size;
  const float* x = (const float*)d_in[0];
  const float* Wqkv = (const float*)d_in[1];
  const float* bqkv = (const float*)d_in[2];
  float* out = (float*)d_out;

  f16* xf = (f16*)d_ws;                  // [8192][1024]
  f16* wf = xf + 8388608;                // [3072][1024]
  f16* qf = wf + 3145728;                // fragment layouts: [bh][t][ki][ni][lane][8]
  f16* kf = qf + 8388608;
  f16* vf = kf + 8388608;
  // total ws use: ~74 MB

  cvt_kernel<<<2048, 256, 0, stream>>>(x, xf, 8388608 / 4);
  cvt_kernel<<<768, 256, 0, stream>>>(Wqkv, wf, 3145728 / 4);
  gemm_qkv<<<1536, 256, 0, stream>>>(xf, wf, bqkv, qf, kf, vf);
  attn_kernel<<<1024, 256, 0, stream>>>(qf, kf, vf, out);
}

// Round 10
// 254.575 us; speedup vs baseline: 1.0223x; 1.0223x over previous
//
#include <hip/hip_runtime.h>

typedef unsigned short u16;
typedef unsigned int u32;
typedef _Float16 f16;
typedef __attribute__((ext_vector_type(8))) f16 half8;   // 8 fp16 = 4 VGPR MFMA operand
typedef __attribute__((ext_vector_type(4))) f16 half4;
typedef __attribute__((ext_vector_type(4))) float f32x4;

#define MFMA16(a, b, c) __builtin_amdgcn_mfma_f32_16x16x32_f16((a), (b), (c), 0, 0, 0)

static __device__ __forceinline__ void gload16(const void* g, void* l) {
  __builtin_amdgcn_global_load_lds(
      (const __attribute__((address_space(1))) void*)g,
      (__attribute__((address_space(3))) void*)l, 16, 0, 0);
}
// swizzled LDS read: rows are 128B; physical col = col ^ ((row&7)<<4)  (T2 st-style swizzle)
static __device__ __forceinline__ half8 lds8h(const f16* base, int row, int colb) {
  int phys = row * 128 + (colb ^ ((row & 7) << 4));
  return *(const half8*)((const char*)base + phys);
}

// ---------------- convert: fp32 -> fp16 (single; products exact in fp32 accum) ----------------
__global__ void cvt_kernel(const float* __restrict__ in, f16* __restrict__ o, int n4) {
  int i = blockIdx.x * blockDim.x + threadIdx.x;
  int stride = gridDim.x * blockDim.x;
  for (; i < n4; i += stride) {
    float4 v = ((const float4*)in)[i];
    half4 h;
    h.x = (f16)v.x; h.y = (f16)v.y; h.z = (f16)v.z; h.w = (f16)v.w;
    *(half4*)(o + (size_t)i * 4) = h;
  }
}

// ---------------- QKV projection GEMM (fp16, L2-fit block order, 3 blocks/CU) ----------------
// C[8192][3072] = X[8192][1024] @ W[3072][1024]^T + b
// XCD decode is mt-fastest within each XCD: x=L&7, s=L>>3, ct=s>>3, mt=x*8+(s&7).
// Concurrent ~64-96 blocks/XCD then cover 8 mt x ~8-12 ct -> A+B working set ~4-5MB = L2-fit
// (was ct-fastest: 24 B-panels = 6MB > 4MB L2 -> ~380MB HBM re-fetch).
// Fragment layout out: [bh][t(32)][ki(2)][ni(4)][lane(64)][e(8)], LDS-staged epilogue.
__global__ __launch_bounds__(256, 3) void gemm_qkv(
    const f16* __restrict__ xf, const f16* __restrict__ wf,
    const float* __restrict__ bias,
    f16* __restrict__ qf, f16* __restrict__ kf, f16* __restrict__ vf) {
  __shared__ __align__(16) f16 smem[16384];          // sA | sB, reused as 4x4096 staging
  f16* sA = smem;
  f16* sB = smem + 8192;
  const int L = blockIdx.x;
  const int x8 = L & 7, s = L >> 3;          // XCD round-robin assumption
  const int ct = s >> 3;                     // [0,24)
  const int mt = x8 * 8 + (s & 7);           // [0,64); bijective overall
  const int c0 = ct * 128, m0 = mt * 128;
  const int tid = threadIdx.x, lane = tid & 63, w = tid >> 6;
  const int wm = w >> 1, wn = w & 1;
  f32x4 acc[4][4] = {};

  for (int t = 0; t < 16; ++t) {
    const int k0 = t * 64;
    for (int j = 0; j < 4; ++j) {
      int chunk = w * 4 + j;
      int r = chunk * 8 + (lane >> 3);
      int cb = (lane & 7) * 16;
      int cbs = cb ^ ((r & 7) << 4);    // inverse-swizzled global source, linear LDS dest
      gload16((const char*)(xf + (size_t)(m0 + r) * 1024 + k0) + cbs, (char*)sA + chunk * 1024);
      gload16((const char*)(wf + (size_t)(c0 + r) * 1024 + k0) + cbs, (char*)sB + chunk * 1024);
    }
    asm volatile("s_waitcnt vmcnt(0)" ::: "memory");
    __syncthreads();

    for (int ki = 0; ki < 2; ++ki) {
      const int colb = (ki * 32 + (lane >> 4) * 8) * 2;
      half8 a[4], bfr[4];
      for (int mi = 0; mi < 4; ++mi)
        a[mi] = lds8h(sA, wm * 64 + mi * 16 + (lane & 15), colb);
      for (int ni = 0; ni < 4; ++ni)
        bfr[ni] = lds8h(sB, wn * 64 + ni * 16 + (lane & 15), colb);
      for (int mi = 0; mi < 4; ++mi)
        for (int ni = 0; ni < 4; ++ni)
          acc[mi][ni] = MFMA16(a[mi], bfr[ni], acc[mi][ni]);
    }
    __syncthreads();
  }

  // ---- epilogue: bias + LDS-staged fragment stores ----
  const int g = lane >> 4, cl = lane & 15;
  const int b = m0 >> 11;
  const int n0t = (m0 & 2047) >> 6;
  const int reg = wn * 2 + wm;           // this wave's staging region
  if (ct < 16) {
    for (int ni = 0; ni < 4; ++ni) {
      const int c = c0 + wn * 64 + ni * 16 + cl;
      const float bv = bias[c];
      const int p = ni * 16 + cl;        // == c & 63
      const int kki = p >> 5, lhi = (p >> 3) & 3, e = p & 7;
      for (int mi = 0; mi < 4; ++mi) {
        int off = reg * 4096 + (kki * 4 + mi) * 512 + lhi * 128 + e;
        for (int i = 0; i < 4; ++i)
          smem[off + (g * 4 + i) * 8] = (f16)(acc[mi][ni][i] + bv);
      }
    }
  } else {
    for (int ni = 0; ni < 4; ++ni) {
      const int c = c0 + wn * 64 + ni * 16 + cl;
      const float bv = bias[c];
      const int p = ni * 16 + cl;
      const int niv = p >> 4, lane_lo = p & 15;
      for (int mi = 0; mi < 4; ++mi) {
        const int kki = mi >> 1;
        for (int i = 0; i < 4; ++i) {
          const int lhi = (mi & 1) * 2 + (g >> 1);
          const int e = (g & 1) * 4 + i;
          smem[reg * 4096 + (kki * 4 + niv) * 512 + (lhi * 16 + lane_lo) * 8 + e] =
              (f16)(acc[mi][ni][i] + bv);
        }
      }
    }
  }
  __syncthreads();
  // copy out: wave w copies the region written by wave (w&1)*2+(w>>1)'s... i.e. region rw
  {
    const int rw = (w & 1) * 2 + (w >> 1);
    const int h_idx = rw >> 1, t_idx = rw & 1;
    f16* dst; int hbase;
    if (ct < 8)       { dst = qf; hbase = c0 >> 6; }
    else if (ct < 16) { dst = kf; hbase = (c0 - 1024) >> 6; }
    else              { dst = vf; hbase = (c0 - 2048) >> 6; }
    size_t gbase = (((size_t)(b * 16 + hbase + h_idx) * 32) + (size_t)(n0t + t_idx)) * 4096;
    for (int j = 0; j < 8; ++j)
      *(float4*)(dst + gbase + (size_t)j * 512 + (size_t)lane * 8) =
          *(const float4*)(smem + rw * 4096 + j * 512 + lane * 8);
  }
}

// ---------------- flash attention (fp16, swapped softmax, defer-max) ----------------
// Grid 1024: xcd=bid&7, bh=xcd*8+(li>>4), qt=li&15; 4 waves x 32 q-rows.
// Swapped QK^T: S^T = K.Q^T -> col=q=lane&15, row=kv; in-register row softmax + 2 shfls.
// T13 defer-max (THR=8): skip corr/rescale while tile max stays within 8 of running max.
__global__ __launch_bounds__(256, 4) void attn_kernel(
    const f16* __restrict__ qf, const f16* __restrict__ kf,
    const f16* __restrict__ vf, float* __restrict__ out) {
  __shared__ __align__(16) f16 pbuf[4][32 * 72];

  const int tid = threadIdx.x, lane = tid & 63, w = tid >> 6;
  const int bid = blockIdx.x;
  const int xcd = bid & 7, li = bid >> 3;
  const int bh = xcd * 8 + (li >> 4);
  const int qt = li & 15;
  const int g = lane >> 4, q = lane & 15;
  const size_t bhbase = (size_t)bh * 32 * 4096;   // per t: 2ki*4ni*512 = 4096 f16

  // Q fragments — used as B-operand (same per-lane layout as A)
  half8 qfr[2][2];
  for (int mi = 0; mi < 2; ++mi) {
    int idx = 2 * w + mi;
    int t = qt * 2 + (idx >> 2), nni = idx & 3;
    for (int ki = 0; ki < 2; ++ki) {
      size_t a = bhbase + (((size_t)t * 2 + ki) * 4 + nni) * 512 + (size_t)lane * 8;
      qfr[mi][ki] = *(const half8*)(qf + a);
    }
  }

  f32x4 oaccT[2][4] = {};                 // [mi][d-block]: col=q, row=d
  float mrow[2], lrow[2];
  for (int mi = 0; mi < 2; ++mi) { mrow[mi] = -3.0e38f; lrow[mi] = 0.f; }

  for (int t = 0; t < 32; ++t) {
    const size_t tb = bhbase + (size_t)t * 4096;

    // S^T = K Q^T ; K fragments as A-operand, straight from global (L2-resident)
    f32x4 sacc[2][4] = {};                // [mi][kv-block]: col=q, row=kv
    for (int ki = 0; ki < 2; ++ki) {
      half8 khf[4];
      for (int ni = 0; ni < 4; ++ni)
        khf[ni] = *(const half8*)(kf + tb + (((size_t)ki * 4 + ni) * 64 + lane) * 8);
      for (int mi = 0; mi < 2; ++mi)
        for (int ni = 0; ni < 4; ++ni)
          sacc[mi][ni] = MFMA16(khf[ni], qfr[mi][ki], sacc[mi][ni]);
    }

    // issue V fragment loads; latency hides under softmax
    half8 vfr[2][4];
    for (int ki = 0; ki < 2; ++ki)
      for (int ni = 0; ni < 4; ++ni)
        vfr[ki][ni] = *(const half8*)(vf + tb + (((size_t)ki * 4 + ni) * 64 + lane) * 8);

    // softmax: per mi, each lane owns q-row = lane&15; 16 kv values in-register
    for (int mi = 0; mi < 2; ++mi) {
      float a0 = fmaxf(fmaxf(sacc[mi][0][0], sacc[mi][0][1]), fmaxf(sacc[mi][0][2], sacc[mi][0][3]));
      float a1 = fmaxf(fmaxf(sacc[mi][1][0], sacc[mi][1][1]), fmaxf(sacc[mi][1][2], sacc[mi][1][3]));
      float a2 = fmaxf(fmaxf(sacc[mi][2][0], sacc[mi][2][1]), fmaxf(sacc[mi][2][2], sacc[mi][2][3]));
      float a3 = fmaxf(fmaxf(sacc[mi][3][0], sacc[mi][3][1]), fmaxf(sacc[mi][3][2], sacc[mi][3][3]));
      float mx = fmaxf(fmaxf(a0, a1), fmaxf(a2, a3));
      mx = fmaxf(mx, __shfl_xor(mx, 16));
      mx = fmaxf(mx, __shfl_xor(mx, 32));
      float mnew;
      if (__all(mx <= mrow[mi] + 8.f)) {
        mnew = mrow[mi];                    // defer: P bounded by e^8, no rescale
      } else {
        mnew = fmaxf(mrow[mi], mx);
        float corr = __expf(mrow[mi] - mnew);
        mrow[mi] = mnew;
        lrow[mi] *= corr;
        for (int ni = 0; ni < 4; ++ni)
          for (int i = 0; i < 4; ++i) oaccT[mi][ni][i] *= corr;
      }
      float rs = 0.f;
      const int prow = mi * 16 + q;
      for (int ni = 0; ni < 4; ++ni) {
        float p0 = __expf(sacc[mi][ni][0] - mnew);
        float p1 = __expf(sacc[mi][ni][1] - mnew);
        float p2 = __expf(sacc[mi][ni][2] - mnew);
        float p3 = __expf(sacc[mi][ni][3] - mnew);
        rs += (p0 + p1) + (p2 + p3);
        half4 pk;
        pk.x = (f16)p0; pk.y = (f16)p1; pk.z = (f16)p2; pk.w = (f16)p3;
        *(half4*)&pbuf[w][prow * 72 + ni * 16 + g * 4] = pk;
      }
      rs += __shfl_xor(rs, 16);
      rs += __shfl_xor(rs, 32);
      lrow[mi] += rs;
    }

    // O^T += V^T P^T  (A = vf fragment rows=d; B = P rows=q from per-wave pbuf)
    for (int ki = 0; ki < 2; ++ki) {
      half8 pf[2];
      for (int mi = 0; mi < 2; ++mi)
        pf[mi] = *(const half8*)&pbuf[w][(mi * 16 + q) * 72 + ki * 32 + g * 8];
      for (int ni = 0; ni < 4; ++ni)
        for (int mi = 0; mi < 2; ++mi)
          oaccT[mi][ni] = MFMA16(vfr[ki][ni], pf[mi], oaccT[mi][ni]);
    }
  }

  // epilogue: O^T/l -> out (faithful (B,H,N,pd) flat, fp32). col=q, row=d.
  for (int mi = 0; mi < 2; ++mi) {
    float inv = 1.f / lrow[mi];
    int grow = qt * 128 + w * 32 + mi * 16 + q;
    size_t obase = ((size_t)bh * 2048 + grow) * 64;
    for (int ni = 0; ni < 4; ++ni)
      for (int i = 0; i < 4; ++i)
        out[obase + ni * 16 + g * 4 + i] = oaccT[mi][ni][i] * inv;
  }
}

extern "C" void kernel_launch(void* const* d_in, const int* in_sizes, int n_in,
                              void* d_out, int out_size, void* d_ws, size_t ws_size,
                              hipStream_t stream) {
  (void)in_sizes; (void)n_in; (void)out_size; (void)ws_size;
  const float* x = (const float*)d_in[0];
  const float* Wqkv = (const float*)d_in[1];
  const float* bqkv = (const float*)d_in[2];
  float* out = (float*)d_out;

  f16* xf = (f16*)d_ws;                  // [8192][1024]
  f16* wf = xf + 8388608;                // [3072][1024]
  f16* qf = wf + 3145728;                // fragment layouts: [bh][t][ki][ni][lane][8]
  f16* kf = qf + 8388608;
  f16* vf = kf + 8388608;
  // total ws use: ~74 MB

  cvt_kernel<<<2048, 256, 0, stream>>>(x, xf, 8388608 / 4);
  cvt_kernel<<<768, 256, 0, stream>>>(Wqkv, wf, 3145728 / 4);
  gemm_qkv<<<1536, 256, 0, stream>>>(xf, wf, bqkv, qf, kf, vf);
  attn_kernel<<<1024, 256, 0, stream>>>(qf, kf, vf, out);
}